// Round 8
// baseline (305.234 us; speedup 1.0000x reference)
//
#include <hip/hip_runtime.h>
#include <hip/hip_bf16.h>

typedef __bf16 bf16_t;
typedef bf16_t bf16x8 __attribute__((ext_vector_type(8)));
typedef float floatx4 __attribute__((ext_vector_type(4)));

#define MFMA16(a, b, c) __builtin_amdgcn_mfma_f32_16x16x32_bf16((a), (b), (c), 0, 0, 0)

// ---------------------------------------------------------------------------
// One-time weight convert fp32 -> bf16, PRE-SWIZZLED into MFMA fragment order.
// QKV region (wb[0..196607]): 48 col16-chunks x 8 k. chunk = c*8 + k,
//   512 bf16/chunk; element (lane,d) =
//   w_qkv[(c*16 + (lane&15))*256 + k*32 + (lane>>4)*8 + d].
// PROJ region (wb[196608..262143]): chunk = p*16 + k*2 + j; element (lane,d) =
//   w_proj[(p*32 + j*16 + (lane&15))*256 + k*32 + (lane>>4)*8 + d].
// ---------------------------------------------------------------------------
__global__ __launch_bounds__(256) void wconv_kernel(
    const float* __restrict__ w_qkv, const float* __restrict__ w_proj,
    bf16_t* __restrict__ wb)
{
  int i = blockIdx.x * 256 + threadIdx.x;      // 0 .. 32767, one 16B chunk each
  const float* src;
  bf16_t* dst;
  if (i < 24576) {                             // qkv: 384 chunks x 64 lanes
    int chunk = i >> 6, l = i & 63;
    int c = chunk >> 3, k = chunk & 7;
    int col = c * 16 + (l & 15);
    int kk = k * 32 + (l >> 4) * 8;
    src = w_qkv + col * 256 + kk;
    dst = wb + (i << 3);
  } else {                                     // proj: 128 chunks x 64 lanes
    int ip = i - 24576;
    int chunk = ip >> 6, l = ip & 63;
    int p = chunk >> 4, rem = chunk & 15, k = rem >> 1, j = rem & 1;
    int col = p * 32 + j * 16 + (l & 15);
    int kk = k * 32 + (l >> 4) * 8;
    src = w_proj + col * 256 + kk;
    dst = wb + 196608 + (ip << 3);
  }
  float4 f0 = ((const float4*)src)[0];
  float4 f1 = ((const float4*)src)[1];
  bf16_t t8[8] = {(bf16_t)f0.x, (bf16_t)f0.y, (bf16_t)f0.z, (bf16_t)f0.w,
                  (bf16_t)f1.x, (bf16_t)f1.y, (bf16_t)f1.z, (bf16_t)f1.w};
  *(uint4*)dst = *(const uint4*)t8;
}

__device__ __forceinline__ void cvt8_store(bf16_t* dst, float4 f0, float4 f1) {
  bf16_t t8[8] = {(bf16_t)f0.x, (bf16_t)f0.y, (bf16_t)f0.z, (bf16_t)f0.w,
                  (bf16_t)f1.x, (bf16_t)f1.y, (bf16_t)f1.z, (bf16_t)f1.w};
  *(uint4*)dst = *(const uint4*)t8;
}

// ---------------------------------------------------------------------------
// Fully fused per-window kernel (grid 2048, 512 thr, 2 blocks/CU).
// LDS life-cycle:
//   Xs[49][264]: X  -> (after X rows die per M-pass) V (cols 0..255)
//   QK[49][520]: Q (0..255) | K (256..511)
//                -> probs overlay K cols 320..383 (f16, after K dead)
//                -> scrambled pre overwrites Q cols 0..255 (after Q dead)
// Phases: stage X | QKV gemm pass0 (rows 0-31) | b | V0->Xs, pass1 (rows
// 32-48) | b | V1->Xs, softmax scores (392 thr, regs) | b | probs->LDS | b |
// PV 784 tasks + scrambled pre write | b | proj gemm + bias -> out.
// Scramble: channel c of token t -> flat = (c>>5)*1568 + t*32 + (c&31),
// row flat>>8, col flat&255 (window-local; verified R2-R7).
// ---------------------------------------------------------------------------
#define XS_S 264   // 528B row stride
#define QK_S 520   // 1040B row stride

__global__ __launch_bounds__(512, 4) void fused_kernel(
    const float* __restrict__ x,
    const bf16_t* __restrict__ wb,
    const float* __restrict__ b_proj,
    float* __restrict__ out)
{
  __shared__ __align__(16) bf16_t Xs[49][XS_S];   // 25.9 KB
  __shared__ __align__(16) bf16_t QK[49][QK_S];   // 51.0 KB

  const int n = blockIdx.x;              // window id 0..2047
  const int b = n >> 6, wh = (n >> 3) & 7, ww = n & 7;
  const int rowbase = b * 3136 + wh * 392 + ww * 7;
  const int tid = threadIdx.x;
  const int wave = tid >> 6, lane = tid & 63, quad = lane >> 4, l16 = lane & 15;
  const float scale = 0.17677669529663687f;       // 32^-0.5

  // bias fragments (issued early, used at the very end)
  const float bv0 = b_proj[wave * 32 + l16];
  const float bv1 = b_proj[wave * 32 + 16 + l16];

  // ---- P0: stage X (49 x 256 fp32 -> bf16), 1568 chunk-tasks ----
  for (int idx = tid; idx < 1568; idx += 512) {
    int s = idx >> 5, g = (idx & 31) * 8;
    int srow = (s / 7) * 56 + (s % 7);
    const float* p = x + (long)(rowbase + srow) * 256 + g;
    float4 f0 = ((const float4*)p)[0];
    float4 f1 = ((const float4*)p)[1];
    cvt8_store(&Xs[s][g], f0, f1);
  }
  __syncthreads();   // b0: X staged

  // swizzled QKV B loader: frag j of this wave's 96-col panel, k-step k
  auto loadB6 = [&](bf16x8 (&dst)[6], int k) {
    const bf16_t* cb = wb + ((long)(wave * 48 + k) << 9) + lane * 8;
#pragma unroll
    for (int j = 0; j < 6; ++j) dst[j] = *(const bf16x8*)(cb + (j << 12));
  };

  floatx4 acc[2][6];
  auto run_pass = [&](int mp) {      // M-tiles {2mp, 2mp+1}
#pragma unroll
    for (int i = 0; i < 2; ++i)
#pragma unroll
      for (int j = 0; j < 6; ++j) acc[i][j] = (floatx4){0.f, 0.f, 0.f, 0.f};
    bf16x8 Ba[6], Bb[6];
    loadB6(Ba, 0);
#pragma unroll
    for (int k = 0; k < 8; ++k) {
      const bf16x8* cur = (k & 1) ? Bb : Ba;
      if (k < 7) loadB6((k & 1) ? Ba : Bb, k + 1);
      int r0 = mp * 32 + l16;
      int r1 = r0 + 16; if (r1 > 48) r1 = 48;
      bf16x8 A0 = *(const bf16x8*)(&Xs[r0][k * 32 + quad * 8]);
      bf16x8 A1 = *(const bf16x8*)(&Xs[r1][k * 32 + quad * 8]);
#pragma unroll
      for (int j = 0; j < 6; ++j) {
        acc[0][j] = MFMA16(A0, cur[j], acc[0][j]);
        acc[1][j] = MFMA16(A1, cur[j], acc[1][j]);
      }
    }
  };
  auto writeQK = [&](int mp) {       // Q,K frags -> QK (safe during pass)
#pragma unroll
    for (int j = 0; j < 6; ++j) {
      int g = wave * 96 + j * 16 + l16;
      if (g < 512) {
#pragma unroll
        for (int i = 0; i < 2; ++i)
#pragma unroll
          for (int r = 0; r < 4; ++r) {
            int row = (mp * 2 + i) * 16 + quad * 4 + r;
            if (row < 49) QK[row][g] = (bf16_t)acc[i][j][r];
          }
      }
    }
  };
  auto writeV = [&](int mp) {        // V frags -> Xs (only after X rows die)
#pragma unroll
    for (int j = 0; j < 6; ++j) {
      int g = wave * 96 + j * 16 + l16;
      if (g >= 512) {
#pragma unroll
        for (int i = 0; i < 2; ++i)
#pragma unroll
          for (int r = 0; r < 4; ++r) {
            int row = (mp * 2 + i) * 16 + quad * 4 + r;
            if (row < 49) Xs[row][g - 512] = (bf16_t)acc[i][j][r];
          }
      }
    }
  };

  // ---- P1: QKV gemm, M-split ----
  run_pass(0);
  writeQK(0);
  __syncthreads();   // b1: X rows 0-31 reads done
  writeV(0);         // V rows 0-31 -> Xs
  run_pass(1);
  writeQK(1);
  __syncthreads();   // b2: X rows 32-48 reads done; Q,K fully visible
  writeV(1);         // V rows 32-48 -> Xs (visible after b3a)

  // ---- P2: softmax scores, 392 tasks (s, h), all in regs ----
  const int s_ = tid >> 3, h_ = tid & 7;
  const bool sm = (tid < 392);
  float sc[8];
  if (sm) {
    float qf[32];
#pragma unroll
    for (int u = 0; u < 4; ++u) {
      bf16x8 qv = *(const bf16x8*)(&QK[s_][h_ * 32 + u * 8]);
#pragma unroll
      for (int d = 0; d < 8; ++d) qf[u * 8 + d] = (float)qv[d];
    }
#pragma unroll
    for (int e = 0; e < 8; ++e) {
      bf16x8 k0 = *(const bf16x8*)(&QK[s_][256 + e * 32]);
      bf16x8 k1 = *(const bf16x8*)(&QK[s_][256 + e * 32 + 8]);
      bf16x8 k2 = *(const bf16x8*)(&QK[s_][256 + e * 32 + 16]);
      bf16x8 k3 = *(const bf16x8*)(&QK[s_][256 + e * 32 + 24]);
      float a = 0.f;
#pragma unroll
      for (int d = 0; d < 8; ++d)
        a += qf[d] * (float)k0[d] + qf[8 + d] * (float)k1[d] +
             qf[16 + d] * (float)k2[d] + qf[24 + d] * (float)k3[d];
      sc[e] = a;
    }
    float mx = -INFINITY;
#pragma unroll
    for (int e = 0; e < 8; ++e) { sc[e] *= scale; mx = fmaxf(mx, sc[e]); }
    float sum = 0.f;
#pragma unroll
    for (int e = 0; e < 8; ++e) { sc[e] = __expf(sc[e] - mx); sum += sc[e]; }
    float rs = 1.0f / sum;
#pragma unroll
    for (int e = 0; e < 8; ++e) sc[e] *= rs;
  }
  __syncthreads();   // b3a: all Q,K reads done -> K region reusable
  if (sm) {          // probs overlay K cols 320..383 (f16)
    _Float16 ph[8];
#pragma unroll
    for (int e = 0; e < 8; ++e) ph[e] = (_Float16)sc[e];
    *(uint4*)((_Float16*)&QK[s_][320] + h_ * 8) = *(const uint4*)ph;
  }
  __syncthreads();   // b3b: probs + V visible

  // ---- P3: PV, 784 tasks (t, j); writes scrambled pre -> QK cols 0..255 ----
  auto pv_task = [&](int idx) {
    int t = idx >> 4, j = idx & 15, j8 = j & 7, h0 = j >> 3;
    float pf[4][8];
#pragma unroll
    for (int m = 0; m < 4; ++m) {
      _Float16 ph[8];
      *(uint4*)ph = *(const uint4*)((const _Float16*)&QK[t][320] + (h0 + 2 * m) * 8);
#pragma unroll
      for (int e = 0; e < 8; ++e) pf[m][e] = (float)ph[e];
    }
    float pr[4][4];
#pragma unroll
    for (int m = 0; m < 4; ++m)
#pragma unroll
      for (int d = 0; d < 4; ++d) pr[m][d] = 0.f;
#pragma unroll
    for (int e = 0; e < 8; ++e) {
      bf16_t v4[4];
      *(uint2*)v4 = *(const uint2*)(&Xs[t][e * 32 + j8 * 4]);
      float vf[4];
#pragma unroll
      for (int d = 0; d < 4; ++d) vf[d] = (float)v4[d];
#pragma unroll
      for (int m = 0; m < 4; ++m) {
        float pe = pf[m][e];
#pragma unroll
        for (int d = 0; d < 4; ++d) pr[m][d] += pe * vf[d];
      }
    }
#pragma unroll
    for (int m = 0; m < 4; ++m) {
      int c = m * 64 + j * 4;                          // output channel
      int flat = (c >> 5) * 1568 + t * 32 + (c & 31);  // window scramble
      bf16_t o4[4] = {(bf16_t)pr[m][0], (bf16_t)pr[m][1],
                      (bf16_t)pr[m][2], (bf16_t)pr[m][3]};
      *(uint2*)(&QK[flat >> 8][flat & 255]) = *(const uint2*)o4;
    }
  };
  pv_task(tid);
  if (tid < 272) pv_task(tid + 512);
  __syncthreads();   // b4: scrambled pre ready

  // ---- P4: proj gemm: out(49x256) = pre @ Wp^T + bias ----
  {
    auto loadBp = [&](bf16x8 (&dst)[2], int k) {
#pragma unroll
      for (int j = 0; j < 2; ++j)
        dst[j] = *(const bf16x8*)(wb + 196608 +
            ((long)(wave * 16 + k * 2 + j) << 9) + lane * 8);
    };
    auto loadA = [&](bf16x8 (&dst)[4], int k) {
#pragma unroll
      for (int i = 0; i < 4; ++i) {
        int mr = i * 16 + l16; if (mr > 48) mr = 48;
        dst[i] = *(const bf16x8*)(&QK[mr][k * 32 + quad * 8]);
      }
    };
    floatx4 pacc[4][2];
#pragma unroll
    for (int i = 0; i < 4; ++i)
#pragma unroll
      for (int j = 0; j < 2; ++j) pacc[i][j] = (floatx4){0.f, 0.f, 0.f, 0.f};
    bf16x8 Aa[4], Ab[4], Ba[2], Bb[2];
    loadA(Aa, 0); loadBp(Ba, 0);
#pragma unroll
    for (int k = 0; k < 8; ++k) {
      const bf16x8* cA = (k & 1) ? Ab : Aa;
      const bf16x8* cB = (k & 1) ? Bb : Ba;
      if (k < 7) { loadA((k & 1) ? Aa : Ab, k + 1); loadBp((k & 1) ? Ba : Bb, k + 1); }
#pragma unroll
      for (int i = 0; i < 4; ++i) {
        pacc[i][0] = MFMA16(cA[i], cB[0], pacc[i][0]);
        pacc[i][1] = MFMA16(cA[i], cB[1], pacc[i][1]);
      }
    }
#pragma unroll
    for (int i = 0; i < 4; ++i)
#pragma unroll
      for (int r = 0; r < 4; ++r) {
        int m = i * 16 + quad * 4 + r;
        if (m < 49) {
          int srow = (m / 7) * 56 + (m % 7);
          float* orow = out + (long)(rowbase + srow) * 256 + wave * 32 + l16;
          orow[0]  = pacc[i][0][r] + bv0;
          orow[16] = pacc[i][1][r] + bv1;
        }
      }
  }
}

// ---------------------------------------------------------------------------
extern "C" void kernel_launch(void* const* d_in, const int* in_sizes, int n_in,
                              void* d_out, int out_size, void* d_ws, size_t ws_size,
                              hipStream_t stream) {
  (void)in_sizes; (void)n_in; (void)out_size; (void)ws_size;
  const float* x      = (const float*)d_in[0];
  const float* w_qkv  = (const float*)d_in[1];
  const float* w_proj = (const float*)d_in[2];
  const float* b_proj = (const float*)d_in[3];
  float* out = (float*)d_out;
  bf16_t* wb = (bf16_t*)d_ws;   // 262144 bf16 = 512 KB

  wconv_kernel<<<dim3(128), 256, 0, stream>>>(w_qkv, w_proj, wb);
  fused_kernel<<<dim3(2048), 512, 0, stream>>>(x, wb, b_proj, out);
}